// Round 2
// baseline (349.924 us; speedup 1.0000x reference)
//
#include <hip/hip_runtime.h>
#include <hip/hip_bf16.h>

#define DIM 128
#define PCH 2048   // edges per partition block

typedef __attribute__((ext_vector_type(8))) short bf16x8;
typedef __attribute__((ext_vector_type(4))) float f32x4;

__device__ __forceinline__ float bfu_lo(unsigned u) { return __uint_as_float(u << 16); }
__device__ __forceinline__ float bfu_hi(unsigned u) { return __uint_as_float(u & 0xffff0000u); }
__device__ __forceinline__ unsigned short f2bf(float f) {
    unsigned u = __float_as_uint(f);
    u += 0x7fffu + ((u >> 16) & 1u);   // round-to-nearest-even
    return (unsigned short)(u >> 16);
}

// stripe id of destination node d (8 stripes over [0,N))
__device__ __forceinline__ int stripe_of(int d, int N) {
    return (int)(((long long)d * 8) / (long long)N);
}
// first node of stripe k = ceil(N*k/8)
__device__ __forceinline__ int stripe_lo(int k, int N) {
    return (int)(((long long)N * k + 7) >> 3);
}

// Zero deg everywhere; block 0 additionally sniffs edge width.
// flags[0]=1 iff edge_index is int64 (odd 32-bit words -- high halves -- all zero).
__global__ void init_detect(const unsigned* ei_w, int* flags, unsigned* deg, int N) {
    int i = blockIdx.x * 256 + threadIdx.x;
    if (i < N) deg[i] = 0u;
    if (blockIdx.x == 0) {
        __shared__ unsigned s_or[256];
        int t = threadIdx.x;
        unsigned o = 0;
        for (int k = t; k < 4096; k += 256) o |= ei_w[2 * k + 1];
        s_or[t] = o;
        __syncthreads();
        for (int s = 128; s > 0; s >>= 1) {
            if (t < s) s_or[t] |= s_or[t + s];
            __syncthreads();
        }
        if (t == 0) flags[0] = (s_or[0] == 0u) ? 1 : 0;
    }
}

__device__ __forceinline__ int edge_at_nt(const void* ei, int idx64, long long pos) {
    return idx64 ? (int)__builtin_nontemporal_load((const long long*)ei + pos)
                 : __builtin_nontemporal_load((const int*)ei + pos);
}

// deg[d] = number of incoming edges at d (self-loop added later as +1).
// Also compacts the edge list into int32 (d,s) pairs for the partition pass.
__global__ void count_pack(const void* ei, unsigned* deg, int2* pairs,
                           const int* flags, int E) {
    int e = blockIdx.x * 256 + threadIdx.x;
    int idx64 = flags[0];
    if (e < E) {
        int d = edge_at_nt(ei, idx64, (long long)E + e);
        int s = edge_at_nt(ei, idx64, e);
        pairs[e] = make_int2(d, s);
        atomicAdd(&deg[d], 1u);
    }
}

// per-block exclusive scan of deg -> row_start (partial), block totals -> blockSums
__global__ void scan1(const unsigned* deg, unsigned* row_start, unsigned* blockSums, int N) {
    __shared__ unsigned wsum[4];
    int t = threadIdx.x;
    int i = blockIdx.x * 256 + t;
    unsigned v = (i < N) ? deg[i] : 0u;
    unsigned s = v;
    int lane = t & 63;
#pragma unroll
    for (int off = 1; off < 64; off <<= 1) {
        unsigned u = __shfl_up(s, off, 64);
        if (lane >= off) s += u;
    }
    int w = t >> 6;
    if (lane == 63) wsum[w] = s;
    __syncthreads();
    unsigned woff = 0;
    for (int j = 0; j < w; j++) woff += wsum[j];
    unsigned excl = woff + s - v;
    if (i < N) row_start[i] = excl;
    if (t == 255) blockSums[blockIdx.x] = woff + s;
}

// single-block exclusive scan of blockSums (nb <= 512)
__global__ void scan2(unsigned* blockSums, int nb) {
    __shared__ unsigned wsum[8];
    int t = threadIdx.x;
    unsigned v = (t < nb) ? blockSums[t] : 0u;
    unsigned s = v;
    int lane = t & 63;
#pragma unroll
    for (int off = 1; off < 64; off <<= 1) {
        unsigned u = __shfl_up(s, off, 64);
        if (lane >= off) s += u;
    }
    int w = t >> 6;
    if (lane == 63) wsum[w] = s;
    __syncthreads();
    unsigned woff = 0;
    for (int j = 0; j < w; j++) woff += wsum[j];
    if (t < nb) blockSums[t] = woff + s - v;
}

// Also initializes the 8 partition bucket cursors: bucket k's region in the
// destination-sorted pair array starts at row_start[stripe_lo(k)] -- exact,
// no slack, robust to any destination distribution.
__global__ void finalize_csr(const unsigned* deg, unsigned* row_start, unsigned* cursor,
                             float* dis, const unsigned* blockSums, unsigned* bcur, int N) {
    int i = blockIdx.x * 256 + threadIdx.x;
    if (i < N) {
        unsigned rs = row_start[i] + blockSums[i >> 8];
        row_start[i] = rs;
        cursor[i] = rs;
        dis[i] = rsqrtf((float)deg[i] + 1.0f);  // +1 self-loop
#pragma unroll
        for (int k = 0; k < 8; k++)
            if (i == stripe_lo(k, N)) bcur[k] = rs;
    }
}

// Block-level 8-way radix partition of (d,s) pairs by destination stripe.
// LDS-staged: histogram -> block prefix -> one global atomicAdd per bucket ->
// LDS scatter -> coalesced flush (avg ~2KB contiguous run per bucket per
// block). Each edge is read ONCE (vs 8x in the old striped fill) and all
// writes are full-line.
__global__ __launch_bounds__(256) void partition8(const int2* __restrict__ pin,
                                                  unsigned* __restrict__ bcur,
                                                  int2* __restrict__ pout, int E, int N) {
    __shared__ unsigned s_hist[8], s_gbase[8], s_off[8];
    __shared__ unsigned s_pref[9];
    __shared__ int2 s_p[PCH];
    int t = threadIdx.x;
    long long base = (long long)blockIdx.x * PCH;
    if (t < 8) { s_hist[t] = 0u; s_off[t] = 0u; }
    __syncthreads();
    int2 my[8]; int mb[8];
#pragma unroll
    for (int j = 0; j < 8; j++) {
        long long e = base + j * 256 + t;
        if (e < E) {
            int2 p = pin[e];
            my[j] = p;
            mb[j] = stripe_of(p.x, N);
            atomicAdd(&s_hist[mb[j]], 1u);
        } else mb[j] = -1;
    }
    __syncthreads();
    if (t == 0) {
        unsigned run = 0;
#pragma unroll
        for (int b = 0; b < 8; b++) { s_pref[b] = run; run += s_hist[b]; }
        s_pref[8] = run;
    }
    __syncthreads();
    if (t < 8 && s_hist[t]) s_gbase[t] = atomicAdd(&bcur[t], s_hist[t]);
    __syncthreads();
#pragma unroll
    for (int j = 0; j < 8; j++)
        if (mb[j] >= 0) {
            unsigned p = s_pref[mb[j]] + atomicAdd(&s_off[mb[j]], 1u);
            s_p[p] = my[j];
        }
    __syncthreads();
    unsigned tot = s_pref[8];
    for (unsigned i = t; i < tot; i += 256) {
        int b = 0;
#pragma unroll
        for (int q = 1; q < 8; q++) if (i >= s_pref[q]) b = q;
        pout[s_gbase[b] + (i - s_pref[b])] = s_p[i];
    }
}

// Final CSR fill from stripe buckets. blockIdx%8 = stripe (= XCD under
// round-robin dispatch). Stripe k's blocks read ONLY bucket k (~E/8 pairs,
// sequential) and scatter into its ~0.8MB col_src segment: total working set
// ~2.4MB < 4MB L2, so dirty lines are never evicted partially -> writebacks
// collapse to payload.
__global__ __launch_bounds__(256) void fill_csr_bucketed(const int2* __restrict__ pairs,
                                                         const unsigned* __restrict__ row_start,
                                                         unsigned* cursor, int* col_src,
                                                         int E, int N) {
    int k = blockIdx.x & 7;
    int chunk = blockIdx.x >> 3;
    int nch = (int)(gridDim.x >> 3);
    unsigned lo = row_start[stripe_lo(k, N)];
    unsigned hi = (k == 7) ? (unsigned)E : row_start[stripe_lo(k + 1, N)];
    const long long* p8 = (const long long*)pairs;
    for (unsigned e = lo + (unsigned)chunk * 256u + (unsigned)threadIdx.x; e < hi;
         e += (unsigned)nch * 256u) {
        long long v = __builtin_nontemporal_load(p8 + e);
        int d = (int)v;
        int s = (int)(v >> 32);
        unsigned pos = atomicAdd(&cursor[d], 1u);
        col_src[pos] = s;
    }
}

// Wt[n][k] = bf16(W[k][n]); W is fp32 [128][128]
__global__ void transposeW(const float* W, unsigned short* Wt) {
    int idx = blockIdx.x * 256 + threadIdx.x;   // 0..DIM*DIM-1
    if (idx < DIM * DIM) {
        int n = idx >> 7, k = idx & 127;
        Wt[idx] = f2bf(W[k * DIM + n]);
    }
}

// xps = dis[row] * (x @ W), bf16 MFMA, fp32 x in / packed-bf16 out (pre-scaled).
// Block = 256 thr = 4 waves, 128 rows/block.
// Operand swap: mfma(Wfrag, Xfrag, acc) -> lane holds out[row=rowBase+l15][col=quad*4+reg]
__global__ __launch_bounds__(256) void gemm_xw(const float* __restrict__ x,
                                               const unsigned short* __restrict__ wt,
                                               const float* __restrict__ dis,
                                               unsigned short* __restrict__ xps, int N) {
    int tid = threadIdx.x;
    int wv = tid >> 6, lane = tid & 63;
    int l15 = lane & 15, quad = lane >> 4;
    int rowBase = blockIdx.x * 128 + wv * 32;

    f32x4 acc[2][8];
#pragma unroll
    for (int mt = 0; mt < 2; mt++)
#pragma unroll
        for (int nt = 0; nt < 8; nt++)
            acc[mt][nt] = (f32x4){0.f, 0.f, 0.f, 0.f};

#pragma unroll
    for (int k0 = 0; k0 < DIM; k0 += 32) {
        bf16x8 aa[2], bb[8];
#pragma unroll
        for (int mt = 0; mt < 2; mt++) {
            int r = rowBase + mt * 16 + l15;
            if (r > N - 1) r = N - 1;           // clamp; garbage rows never stored
            const float* xf = x + (size_t)r * DIM + k0 + quad * 8;
            float4 u0 = ((const float4*)xf)[0];
            float4 u1 = ((const float4*)xf)[1];
            bf16x8 a;
            a[0] = (short)f2bf(u0.x); a[1] = (short)f2bf(u0.y);
            a[2] = (short)f2bf(u0.z); a[3] = (short)f2bf(u0.w);
            a[4] = (short)f2bf(u1.x); a[5] = (short)f2bf(u1.y);
            a[6] = (short)f2bf(u1.z); a[7] = (short)f2bf(u1.w);
            aa[mt] = a;
        }
#pragma unroll
        for (int nt = 0; nt < 8; nt++)
            bb[nt] = *(const bf16x8*)(wt + (size_t)(nt * 16 + l15) * DIM + k0 + quad * 8);
#pragma unroll
        for (int mt = 0; mt < 2; mt++)
#pragma unroll
            for (int nt = 0; nt < 8; nt++)
                acc[mt][nt] = __builtin_amdgcn_mfma_f32_16x16x32_bf16(bb[nt], aa[mt], acc[mt][nt], 0, 0, 0);
    }

#pragma unroll
    for (int mt = 0; mt < 2; mt++) {
        int r = rowBase + mt * 16 + l15;
        if (r < N) {
            float sc = dis[r];                  // pre-scale by source-side dis
#pragma unroll
            for (int nt = 0; nt < 8; nt++) {
                int c0 = nt * 16 + quad * 4;
                ushort4 o;
                o.x = f2bf(acc[mt][nt][0] * sc);
                o.y = f2bf(acc[mt][nt][1] * sc);
                o.z = f2bf(acc[mt][nt][2] * sc);
                o.w = f2bf(acc[mt][nt][3] * sc);
                *(ushort4*)(xps + (size_t)r * DIM + c0) = o;
            }
        }
    }
}

// One wave per node. 16 lanes per edge row (uint4 = 16B = 8 bf16 each), 4 edge
// slots per wave, inner loop unrolled x2 (8 slots / iter) for MLP. Indices are
// prefetched 64-at-a-time (one coalesced load) and shfl-broadcast. Self-loop is
// virtual slot `cnt` (index wid). out[d] = dis[d] * sum(xps).
__global__ __launch_bounds__(256) void aggregate(const unsigned short* __restrict__ xps,
                                                 const unsigned* __restrict__ row_start,
                                                 const unsigned* __restrict__ deg,
                                                 const float* __restrict__ dis,
                                                 const int* __restrict__ col_src,
                                                 float* __restrict__ out, int N) {
    int wid = (int)((blockIdx.x * 256 + threadIdx.x) >> 6);
    if (wid >= N) return;
    int lane = threadIdx.x & 63;
    int grp = lane >> 4, lin = lane & 15;
    const uint4* xp4 = (const uint4*)xps;       // row = 16 x uint4

    float acc[8];
#pragma unroll
    for (int j = 0; j < 8; j++) acc[j] = 0.f;

    unsigned rs = row_start[wid];
    unsigned cnt = deg[wid];
    unsigned tot = cnt + 1;                      // + virtual self slot

    for (unsigned base = 0; base < tot; base += 64) {
        unsigned slot = base + (unsigned)lane;
        int idx = (slot < cnt) ? col_src[rs + slot] : wid;   // invalid/self -> wid (safe)
        unsigned rem = tot - base; if (rem > 64) rem = 64;
        for (unsigned q = 0; q * 8 < rem; q++) {
            unsigned sl0 = q * 8 + (unsigned)grp;
            unsigned sl1 = sl0 + 4;
            int s0 = __shfl(idx, (int)sl0, 64);
            int s1 = __shfl(idx, (int)sl1, 64);
            float m0 = (sl0 < rem) ? 1.f : 0.f;
            float m1 = (sl1 < rem) ? 1.f : 0.f;
            uint4 v0 = xp4[(size_t)s0 * 16 + lin];
            uint4 v1 = xp4[(size_t)s1 * 16 + lin];
            acc[0] = fmaf(bfu_lo(v0.x), m0, acc[0]);
            acc[1] = fmaf(bfu_hi(v0.x), m0, acc[1]);
            acc[2] = fmaf(bfu_lo(v0.y), m0, acc[2]);
            acc[3] = fmaf(bfu_hi(v0.y), m0, acc[3]);
            acc[4] = fmaf(bfu_lo(v0.z), m0, acc[4]);
            acc[5] = fmaf(bfu_hi(v0.z), m0, acc[5]);
            acc[6] = fmaf(bfu_lo(v0.w), m0, acc[6]);
            acc[7] = fmaf(bfu_hi(v0.w), m0, acc[7]);
            acc[0] = fmaf(bfu_lo(v1.x), m1, acc[0]);
            acc[1] = fmaf(bfu_hi(v1.x), m1, acc[1]);
            acc[2] = fmaf(bfu_lo(v1.y), m1, acc[2]);
            acc[3] = fmaf(bfu_hi(v1.y), m1, acc[3]);
            acc[4] = fmaf(bfu_lo(v1.z), m1, acc[4]);
            acc[5] = fmaf(bfu_hi(v1.z), m1, acc[5]);
            acc[6] = fmaf(bfu_lo(v1.w), m1, acc[6]);
            acc[7] = fmaf(bfu_hi(v1.w), m1, acc[7]);
        }
    }

    // reduce across the 4 groups (lanes differing in bits 4 and 5)
#pragma unroll
    for (int j = 0; j < 8; j++) {
        acc[j] += __shfl_xor(acc[j], 16, 64);
        acc[j] += __shfl_xor(acc[j], 32, 64);
    }

    float di = dis[wid];
    if (grp < 2) {                               // 32 lanes store the 512B row
        int jb = (grp & 1) * 4;
        float4 o;
        o.x = acc[jb + 0] * di;
        o.y = acc[jb + 1] * di;
        o.z = acc[jb + 2] * di;
        o.w = acc[jb + 3] * di;
        *(float4*)(out + (size_t)wid * DIM + lin * 8 + jb) = o;
    }
}

extern "C" void kernel_launch(void* const* d_in, const int* in_sizes, int n_in,
                              void* d_out, int out_size, void* d_ws, size_t ws_size,
                              hipStream_t stream) {
    const int N = in_sizes[0] / DIM;
    const int E = in_sizes[1] / 2;
    const float* x = (const float*)d_in[0];                     // fp32 [N][128]
    const void* ei = d_in[1];                                   // int32 or int64 [2][E]
    const float* W = (const float*)d_in[2];                     // fp32 [128][128]
    float* out = (float*)d_out;                                 // fp32 [N][128]

    char* wsp = (char*)d_ws;
    size_t off = 0;
    auto alloc = [&](size_t b) { void* p = wsp + off; off += (b + 255) & ~(size_t)255; return p; };
    int*      flags      = (int*)alloc(256);
    unsigned* deg        = (unsigned*)alloc((size_t)N * 4);
    unsigned* row_start  = (unsigned*)alloc((size_t)N * 4);
    unsigned* cursor     = (unsigned*)alloc((size_t)N * 4);
    unsigned* blockSums  = (unsigned*)alloc(4096);
    float*    dis        = (float*)alloc((size_t)N * 4);
    unsigned* bcur       = (unsigned*)alloc(256);
    int*      col_src    = (int*)alloc((size_t)E * 4);
    unsigned short* Wt   = (unsigned short*)alloc((size_t)DIM * DIM * 2);
    unsigned short* xps  = (unsigned short*)alloc((size_t)N * DIM * 2);

    // pairs_in aliases the (not-yet-live) xps region; pairs_out gets fresh ws
    // if the workspace allows, else the upper half of xps (2*E*8 == N*DIM*2
    // exactly for this problem). Both are dead before gemm_xw writes xps.
    int2* pairs_in = (int2*)xps;
    int2* pairs_out;
    if (off + (size_t)E * 8 + 256 <= ws_size) {
        pairs_out = (int2*)alloc((size_t)E * 8);
    } else {
        pairs_out = pairs_in + E;
    }

    int nb = (N + 255) / 256;
    init_detect<<<nb, 256, 0, stream>>>((const unsigned*)ei, flags, deg, N);
    count_pack<<<(E + 255) / 256, 256, 0, stream>>>(ei, deg, pairs_in, flags, E);
    scan1<<<nb, 256, 0, stream>>>(deg, row_start, blockSums, N);
    scan2<<<1, 512, 0, stream>>>(blockSums, nb);
    finalize_csr<<<nb, 256, 0, stream>>>(deg, row_start, cursor, dis, blockSums, bcur, N);
    partition8<<<(E + PCH - 1) / PCH, 256, 0, stream>>>(pairs_in, bcur, pairs_out, E, N);
    int nchunks = (E / 8 + 1023) / 1024 + 1;     // ~4 grid-stride iters/block
    fill_csr_bucketed<<<nchunks * 8, 256, 0, stream>>>(pairs_out, row_start, cursor, col_src, E, N);
    transposeW<<<(DIM * DIM + 255) / 256, 256, 0, stream>>>(W, Wt);
    gemm_xw<<<(N + 127) / 128, 256, 0, stream>>>(x, Wt, dis, xps, N);
    aggregate<<<(N + 3) / 4, 256, 0, stream>>>(xps, row_start, deg, dis, col_src, out, N);
}

// Round 4
// 260.051 us; speedup vs baseline: 1.3456x; 1.3456x over previous
//
#include <hip/hip_runtime.h>
#include <hip/hip_bf16.h>

#define DIM 128
#define PCH 4096   // edges per partition block (LDS-staged)

typedef __attribute__((ext_vector_type(8))) short bf16x8;
typedef __attribute__((ext_vector_type(4))) float f32x4;

__device__ __forceinline__ float bfu_lo(unsigned u) { return __uint_as_float(u << 16); }
__device__ __forceinline__ float bfu_hi(unsigned u) { return __uint_as_float(u & 0xffff0000u); }
__device__ __forceinline__ unsigned short f2bf(float f) {
    unsigned u = __float_as_uint(f);
    u += 0x7fffu + ((u >> 16) & 1u);   // round-to-nearest-even
    return (unsigned short)(u >> 16);
}

__device__ __forceinline__ int edge_at(const void* ei, int idx64, long long pos) {
    return idx64 ? (int)__builtin_nontemporal_load((const long long*)ei + pos)
                 : __builtin_nontemporal_load((const int*)ei + pos);
}

// flags[0]=1 iff edge_index is int64 (odd 32-bit words -- high halves -- all zero).
// Also zeroes the 512-entry bucket-count array.
__global__ void init_detect(const unsigned* ei_w, int* flags, unsigned* bcnt, int E) {
    __shared__ unsigned s_or[256];
    int t = threadIdx.x;
    bcnt[t] = 0u;
    bcnt[256 + t] = 0u;
    unsigned o = 0;
    int lim = (E < 4096) ? E : 4096;
    for (int k = t; k < lim; k += 256) o |= ei_w[2 * k + 1];
    s_or[t] = o;
    __syncthreads();
    for (int s = 128; s > 0; s >>= 1) {
        if (t < s) s_or[t] |= s_or[t + s];
        __syncthreads();
    }
    if (t == 0) flags[0] = (s_or[0] == 0u) ? 1 : 0;
}

// Bucket histogram of destinations. Per-edge increments hit LDS; global
// atomics are only the per-block flush (<=512 per block, hot 2KB array).
// This replaces the 1.6M scattered global atomicAdds of the old count pass
// (each cost a full 64B line transaction at the coherence point -- that was
// the 68us / WRITE_SIZE=62MB dispatch).
__global__ __launch_bounds__(256) void hist_pass(const void* ei, const int* flags,
                                                 unsigned* bcnt, int E, int shift) {
    __shared__ unsigned s_h[512];
    int t = threadIdx.x;
    for (int i = t; i < 512; i += 256) s_h[i] = 0u;
    __syncthreads();
    int idx64 = flags[0];
    long long stride = (long long)gridDim.x * 256;
    for (long long e = (long long)blockIdx.x * 256 + t; e < E; e += stride) {
        int d = edge_at(ei, idx64, (long long)E + e);
        atomicAdd(&s_h[d >> shift], 1u);
    }
    __syncthreads();
    for (int i = t; i < 512; i += 256)
        if (s_h[i]) atomicAdd(&bcnt[i], s_h[i]);
}

// Exclusive scan of 512 bucket counts -> bucket edge bases + write cursors.
// bbase[B] lands at E automatically (all buckets >= B are empty).
__global__ void scan_buckets(const unsigned* bcnt, unsigned* bbase, unsigned* bcur) {
    __shared__ unsigned wsum[8];
    int t = threadIdx.x;
    unsigned v = bcnt[t];
    unsigned s = v;
    int lane = t & 63;
#pragma unroll
    for (int off = 1; off < 64; off <<= 1) {
        unsigned u = __shfl_up(s, off, 64);
        if (lane >= off) s += u;
    }
    int w = t >> 6;
    if (lane == 63) wsum[w] = s;
    __syncthreads();
    unsigned woff = 0;
    for (int j = 0; j < w; j++) woff += wsum[j];
    unsigned excl = woff + s - v;
    bbase[t] = excl;
    bcur[t] = excl;
    if (t == 511) bbase[512] = excl + v;
}

// LDS-staged partition of raw edges into destination buckets. Each edge is
// read once; per-edge position atomics are LDS; global atomics are one per
// non-empty bucket per block (on a hot 2KB cursor array). Flush writes are
// cursor-ordered contiguous runs -> plain stores that write-combine in L2.
__global__ __launch_bounds__(256) void partition(const void* ei, const int* flags,
                                                 unsigned* bcur, long long* pout,
                                                 int E, int B, int shift) {
    __shared__ unsigned s_hist[512], s_off[512], s_gbase[512], s_pref[512];
    __shared__ unsigned wsum[4];
    __shared__ long long s_p[PCH];
    int t = threadIdx.x;
    long long base = (long long)blockIdx.x * PCH;
    for (int i = t; i < 512; i += 256) { s_hist[i] = 0u; s_off[i] = 0u; }
    __syncthreads();
    int idx64 = flags[0];
    int d_[PCH / 256], s_[PCH / 256];
#pragma unroll 4
    for (int j = 0; j < PCH / 256; j++) {
        long long e = base + j * 256 + t;
        if (e < E) {
            d_[j] = edge_at(ei, idx64, (long long)E + e);
            s_[j] = edge_at(ei, idx64, e);
            atomicAdd(&s_hist[d_[j] >> shift], 1u);
        } else d_[j] = -1;
    }
    __syncthreads();
    // exclusive scan of 512 counts, 2 per thread
    unsigned v0 = s_hist[2 * t], v1 = s_hist[2 * t + 1];
    unsigned ps = v0 + v1;
    unsigned s = ps;
    int lane = t & 63;
#pragma unroll
    for (int off = 1; off < 64; off <<= 1) {
        unsigned u = __shfl_up(s, off, 64);
        if (lane >= off) s += u;
    }
    int w = t >> 6;
    if (lane == 63) wsum[w] = s;
    __syncthreads();
    unsigned woff = 0;
    for (int j = 0; j < w; j++) woff += wsum[j];
    unsigned excl = woff + s - ps;
    s_pref[2 * t] = excl;
    s_pref[2 * t + 1] = excl + v0;
    __syncthreads();
    for (int i = t; i < B; i += 256)
        if (s_hist[i]) s_gbase[i] = atomicAdd(&bcur[i], s_hist[i]);
#pragma unroll 4
    for (int j = 0; j < PCH / 256; j++)
        if (d_[j] >= 0) {
            int b = d_[j] >> shift;
            unsigned p = s_pref[b] + atomicAdd(&s_off[b], 1u);
            s_p[p] = ((long long)s_[j] << 32) | (unsigned)d_[j];
        }
    __syncthreads();
    long long rem = (long long)E - base;
    unsigned tot = (rem < PCH) ? (unsigned)rem : (unsigned)PCH;
    for (unsigned i = t; i < tot; i += 256) {
        int lo = 0, hi = B - 1;                 // largest b with s_pref[b] <= i
        while (lo < hi) {
            int mid = (lo + hi + 1) >> 1;
            if (s_pref[mid] <= i) lo = mid; else hi = mid - 1;
        }
        pout[s_gbase[lo] + (i - s_pref[lo])] = s_p[i];
    }
}

// One block per bucket (<=512 nodes). Degree histogram, prefix scan, dis, and
// CSR fill all via LDS counters -- zero global scattered atomics. col_src
// scatter targets a block-local contiguous ~16KB window (L2-resident).
__global__ __launch_bounds__(256) void build_csr(const long long* __restrict__ pairs,
                                                 const unsigned* __restrict__ bbase,
                                                 unsigned* deg, unsigned* row_start,
                                                 float* dis, int* col_src,
                                                 int N, int shift) {
    __shared__ unsigned cnt[512], cur[512], pref[512];
    __shared__ unsigned wsum[4];
    int b = blockIdx.x, t = threadIdx.x;
    int npb = 1 << shift;
    if (npb > 512) npb = 512;                   // defensive; caller guarantees <=512
    int nodeLo = b << shift;
    unsigned lo = bbase[b], hi = bbase[b + 1];
    for (int i = t; i < npb; i += 256) cnt[i] = 0u;
    __syncthreads();
    for (unsigned e = lo + t; e < hi; e += 256) {
        int d = (int)pairs[e];
        atomicAdd(&cnt[d - nodeLo], 1u);
    }
    __syncthreads();
    // exclusive scan of npb (<=512) counts, 2 per thread
    unsigned v0 = (2 * t < npb) ? cnt[2 * t] : 0u;
    unsigned v1 = (2 * t + 1 < npb) ? cnt[2 * t + 1] : 0u;
    unsigned ps = v0 + v1;
    unsigned s = ps;
    int lane = t & 63;
#pragma unroll
    for (int off = 1; off < 64; off <<= 1) {
        unsigned u = __shfl_up(s, off, 64);
        if (lane >= off) s += u;
    }
    int w = t >> 6;
    if (lane == 63) wsum[w] = s;
    __syncthreads();
    unsigned woff = 0;
    for (int j = 0; j < w; j++) woff += wsum[j];
    unsigned excl = woff + s - ps;
    if (2 * t < npb) pref[2 * t] = excl;
    if (2 * t + 1 < npb) pref[2 * t + 1] = excl + v0;
    __syncthreads();
    for (int i = t; i < npb; i += 256) {
        int node = nodeLo + i;
        unsigned rs = lo + pref[i];
        if (node < N) {
            unsigned c = cnt[i];
            deg[node] = c;
            row_start[node] = rs;
            dis[node] = rsqrtf((float)c + 1.0f);   // +1 self-loop
        }
        cur[i] = rs;
    }
    __syncthreads();
    for (unsigned e = lo + t; e < hi; e += 256) {
        long long v = pairs[e];
        int d = (int)v;
        int sv = (int)(v >> 32);
        unsigned pos = atomicAdd(&cur[d - nodeLo], 1u);
        col_src[pos] = sv;
    }
}

// Wt[n][k] = bf16(W[k][n]); W is fp32 [128][128]
__global__ void transposeW(const float* W, unsigned short* Wt) {
    int idx = blockIdx.x * 256 + threadIdx.x;   // 0..DIM*DIM-1
    if (idx < DIM * DIM) {
        int n = idx >> 7, k = idx & 127;
        Wt[idx] = f2bf(W[k * DIM + n]);
    }
}

// xps = dis[row] * (x @ W), bf16 MFMA, fp32 x in / packed-bf16 out (pre-scaled).
// Block = 256 thr = 4 waves, 128 rows/block.
// Operand swap: mfma(Wfrag, Xfrag, acc) -> lane holds out[row=rowBase+l15][col=quad*4+reg]
__global__ __launch_bounds__(256) void gemm_xw(const float* __restrict__ x,
                                               const unsigned short* __restrict__ wt,
                                               const float* __restrict__ dis,
                                               unsigned short* __restrict__ xps, int N) {
    int tid = threadIdx.x;
    int wv = tid >> 6, lane = tid & 63;
    int l15 = lane & 15, quad = lane >> 4;
    int rowBase = blockIdx.x * 128 + wv * 32;

    f32x4 acc[2][8];
#pragma unroll
    for (int mt = 0; mt < 2; mt++)
#pragma unroll
        for (int nt = 0; nt < 8; nt++)
            acc[mt][nt] = (f32x4){0.f, 0.f, 0.f, 0.f};

#pragma unroll
    for (int k0 = 0; k0 < DIM; k0 += 32) {
        bf16x8 aa[2], bb[8];
#pragma unroll
        for (int mt = 0; mt < 2; mt++) {
            int r = rowBase + mt * 16 + l15;
            if (r > N - 1) r = N - 1;           // clamp; garbage rows never stored
            const float* xf = x + (size_t)r * DIM + k0 + quad * 8;
            float4 u0 = ((const float4*)xf)[0];
            float4 u1 = ((const float4*)xf)[1];
            bf16x8 a;
            a[0] = (short)f2bf(u0.x); a[1] = (short)f2bf(u0.y);
            a[2] = (short)f2bf(u0.z); a[3] = (short)f2bf(u0.w);
            a[4] = (short)f2bf(u1.x); a[5] = (short)f2bf(u1.y);
            a[6] = (short)f2bf(u1.z); a[7] = (short)f2bf(u1.w);
            aa[mt] = a;
        }
#pragma unroll
        for (int nt = 0; nt < 8; nt++)
            bb[nt] = *(const bf16x8*)(wt + (size_t)(nt * 16 + l15) * DIM + k0 + quad * 8);
#pragma unroll
        for (int mt = 0; mt < 2; mt++)
#pragma unroll
            for (int nt = 0; nt < 8; nt++)
                acc[mt][nt] = __builtin_amdgcn_mfma_f32_16x16x32_bf16(bb[nt], aa[mt], acc[mt][nt], 0, 0, 0);
    }

#pragma unroll
    for (int mt = 0; mt < 2; mt++) {
        int r = rowBase + mt * 16 + l15;
        if (r < N) {
            float sc = dis[r];                  // pre-scale by source-side dis
#pragma unroll
            for (int nt = 0; nt < 8; nt++) {
                int c0 = nt * 16 + quad * 4;
                ushort4 o;
                o.x = f2bf(acc[mt][nt][0] * sc);
                o.y = f2bf(acc[mt][nt][1] * sc);
                o.z = f2bf(acc[mt][nt][2] * sc);
                o.w = f2bf(acc[mt][nt][3] * sc);
                *(ushort4*)(xps + (size_t)r * DIM + c0) = o;
            }
        }
    }
}

// One wave per node. 16 lanes per edge row (uint4 = 16B = 8 bf16 each), 4 edge
// slots per wave, inner loop unrolled x2 (8 slots / iter) for MLP. Indices are
// prefetched 64-at-a-time (one coalesced load) and shfl-broadcast. Self-loop is
// virtual slot `cnt` (index wid). out[d] = dis[d] * sum(xps).
__global__ __launch_bounds__(256) void aggregate(const unsigned short* __restrict__ xps,
                                                 const unsigned* __restrict__ row_start,
                                                 const unsigned* __restrict__ deg,
                                                 const float* __restrict__ dis,
                                                 const int* __restrict__ col_src,
                                                 float* __restrict__ out, int N) {
    int wid = (int)((blockIdx.x * 256 + threadIdx.x) >> 6);
    if (wid >= N) return;
    int lane = threadIdx.x & 63;
    int grp = lane >> 4, lin = lane & 15;
    const uint4* xp4 = (const uint4*)xps;       // row = 16 x uint4

    float acc[8];
#pragma unroll
    for (int j = 0; j < 8; j++) acc[j] = 0.f;

    unsigned rs = row_start[wid];
    unsigned cnt = deg[wid];
    unsigned tot = cnt + 1;                      // + virtual self slot

    for (unsigned base = 0; base < tot; base += 64) {
        unsigned slot = base + (unsigned)lane;
        int idx = (slot < cnt) ? col_src[rs + slot] : wid;   // invalid/self -> wid (safe)
        unsigned rem = tot - base; if (rem > 64) rem = 64;
        for (unsigned q = 0; q * 8 < rem; q++) {
            unsigned sl0 = q * 8 + (unsigned)grp;
            unsigned sl1 = sl0 + 4;
            int s0 = __shfl(idx, (int)sl0, 64);
            int s1 = __shfl(idx, (int)sl1, 64);
            float m0 = (sl0 < rem) ? 1.f : 0.f;
            float m1 = (sl1 < rem) ? 1.f : 0.f;
            uint4 v0 = xp4[(size_t)s0 * 16 + lin];
            uint4 v1 = xp4[(size_t)s1 * 16 + lin];
            acc[0] = fmaf(bfu_lo(v0.x), m0, acc[0]);
            acc[1] = fmaf(bfu_hi(v0.x), m0, acc[1]);
            acc[2] = fmaf(bfu_lo(v0.y), m0, acc[2]);
            acc[3] = fmaf(bfu_hi(v0.y), m0, acc[3]);
            acc[4] = fmaf(bfu_lo(v0.z), m0, acc[4]);
            acc[5] = fmaf(bfu_hi(v0.z), m0, acc[5]);
            acc[6] = fmaf(bfu_lo(v0.w), m0, acc[6]);
            acc[7] = fmaf(bfu_hi(v0.w), m0, acc[7]);
            acc[0] = fmaf(bfu_lo(v1.x), m1, acc[0]);
            acc[1] = fmaf(bfu_hi(v1.x), m1, acc[1]);
            acc[2] = fmaf(bfu_lo(v1.y), m1, acc[2]);
            acc[3] = fmaf(bfu_hi(v1.y), m1, acc[3]);
            acc[4] = fmaf(bfu_lo(v1.z), m1, acc[4]);
            acc[5] = fmaf(bfu_hi(v1.z), m1, acc[5]);
            acc[6] = fmaf(bfu_lo(v1.w), m1, acc[6]);
            acc[7] = fmaf(bfu_hi(v1.w), m1, acc[7]);
        }
    }

    // reduce across the 4 groups (lanes differing in bits 4 and 5)
#pragma unroll
    for (int j = 0; j < 8; j++) {
        acc[j] += __shfl_xor(acc[j], 16, 64);
        acc[j] += __shfl_xor(acc[j], 32, 64);
    }

    float di = dis[wid];
    if (grp < 2) {                               // 32 lanes store the 512B row
        int jb = (grp & 1) * 4;
        float4 o;
        o.x = acc[jb + 0] * di;
        o.y = acc[jb + 1] * di;
        o.z = acc[jb + 2] * di;
        o.w = acc[jb + 3] * di;
        *(float4*)(out + (size_t)wid * DIM + lin * 8 + jb) = o;
    }
}

extern "C" void kernel_launch(void* const* d_in, const int* in_sizes, int n_in,
                              void* d_out, int out_size, void* d_ws, size_t ws_size,
                              hipStream_t stream) {
    const int N = in_sizes[0] / DIM;
    const int E = in_sizes[1] / 2;
    const float* x = (const float*)d_in[0];                     // fp32 [N][128]
    const void* ei = d_in[1];                                   // int32 or int64 [2][E]
    const float* W = (const float*)d_in[2];                     // fp32 [128][128]
    float* out = (float*)d_out;                                 // fp32 [N][128]

    // bucket geometry: 2^shift nodes per bucket, B <= 512 buckets; npb <= 512
    // (holds for N <= 262144; this problem is N=100000 -> shift=8, B=391)
    int shift = 8;
    while ((((long long)N + (1LL << shift) - 1) >> shift) > 512 && shift < 9) shift++;
    int B = (int)(((long long)N + (1LL << shift) - 1) >> shift);

    char* wsp = (char*)d_ws;
    size_t off = 0;
    auto alloc = [&](size_t b) { void* p = wsp + off; off += (b + 255) & ~(size_t)255; return p; };
    int*      flags      = (int*)alloc(256);
    unsigned* bcnt       = (unsigned*)alloc(512 * 4);
    unsigned* bbase      = (unsigned*)alloc(513 * 4);
    unsigned* bcur       = (unsigned*)alloc(512 * 4);
    unsigned* deg        = (unsigned*)alloc((size_t)N * 4);
    unsigned* row_start  = (unsigned*)alloc((size_t)N * 4);
    float*    dis        = (float*)alloc((size_t)N * 4);
    int*      col_src    = (int*)alloc((size_t)E * 4);
    unsigned short* Wt   = (unsigned short*)alloc((size_t)DIM * DIM * 2);
    unsigned short* xps  = (unsigned short*)alloc((size_t)N * DIM * 2);

    // pairs alias the xps region (E*8 = 12.8MB <= N*DIM*2 = 25.6MB): dead
    // before gemm_xw writes xps (stream-ordered), so no extra workspace.
    long long* pairs = (long long*)xps;
    if ((size_t)E * 8 > (size_t)N * DIM * 2 && off + (size_t)E * 8 <= ws_size)
        pairs = (long long*)alloc((size_t)E * 8);

    init_detect<<<1, 256, 0, stream>>>((const unsigned*)ei, flags, bcnt, E);
    hist_pass<<<512, 256, 0, stream>>>(ei, flags, bcnt, E, shift);
    scan_buckets<<<1, 512, 0, stream>>>(bcnt, bbase, bcur);
    partition<<<(E + PCH - 1) / PCH, 256, 0, stream>>>(ei, flags, bcur, pairs, E, B, shift);
    build_csr<<<B, 256, 0, stream>>>(pairs, bbase, deg, row_start, dis, col_src, N, shift);
    transposeW<<<(DIM * DIM + 255) / 256, 256, 0, stream>>>(W, Wt);
    gemm_xw<<<(N + 127) / 128, 256, 0, stream>>>(x, Wt, dis, xps, N);
    aggregate<<<(N + 3) / 4, 256, 0, stream>>>(xps, row_start, deg, dis, col_src, out, N);
}

// Round 5
// 253.671 us; speedup vs baseline: 1.3794x; 1.0252x over previous
//
#include <hip/hip_runtime.h>
#include <hip/hip_bf16.h>

#define DIM 128
#define PCH 4096   // edges per partition block (LDS-staged)

typedef __attribute__((ext_vector_type(8))) short bf16x8;
typedef __attribute__((ext_vector_type(4))) float f32x4;

__device__ __forceinline__ float bfu_lo(unsigned u) { return __uint_as_float(u << 16); }
__device__ __forceinline__ float bfu_hi(unsigned u) { return __uint_as_float(u & 0xffff0000u); }
__device__ __forceinline__ unsigned short f2bf(float f) {
    unsigned u = __float_as_uint(f);
    u += 0x7fffu + ((u >> 16) & 1u);   // round-to-nearest-even
    return (unsigned short)(u >> 16);
}

__device__ __forceinline__ int edge_at(const void* ei, int idx64, long long pos) {
    return idx64 ? (int)__builtin_nontemporal_load((const long long*)ei + pos)
                 : __builtin_nontemporal_load((const int*)ei + pos);
}

// Block-local edge-width sniff: returns 1 iff edge_index is int64 (odd 32-bit
// words -- high halves -- of the first min(E,4096) entries are all zero).
// Reads 16KB that is L2/L3-hot after the first block; cost ~us. Replaces the
// standalone init_detect dispatch (~10us launch gap each).
__device__ __forceinline__ int detect_idx64(const void* ei, int E, unsigned* s_or, int* s_flag) {
    const unsigned* ei_w = (const unsigned*)ei;
    int t = threadIdx.x;
    unsigned o = 0;
    int lim = (E < 4096) ? E : 4096;
    for (int k = t; k < lim; k += 256) o |= ei_w[2 * k + 1];
    s_or[t] = o;
    __syncthreads();
    for (int s = 128; s > 0; s >>= 1) {
        if (t < s) s_or[t] |= s_or[t + s];
        __syncthreads();
    }
    if (t == 0) *s_flag = (s_or[0] == 0u) ? 1 : 0;
    __syncthreads();
    return *s_flag;
}

// Bucket histogram of destinations (+fused width detect). Per-edge increments
// hit LDS; global atomics are only the per-block flush (<=512 per block, hot
// 2KB array). bcnt must be pre-zeroed (hipMemsetAsync).
__global__ __launch_bounds__(256) void hist_detect(const void* ei, unsigned* bcnt,
                                                   int E, int shift) {
    __shared__ unsigned s_h[512];
    __shared__ unsigned s_or[256];
    __shared__ int s_flag;
    int t = threadIdx.x;
    for (int i = t; i < 512; i += 256) s_h[i] = 0u;
    int idx64 = detect_idx64(ei, E, s_or, &s_flag);
    long long stride = (long long)gridDim.x * 256;
    for (long long e = (long long)blockIdx.x * 256 + t; e < E; e += stride) {
        int d = edge_at(ei, idx64, (long long)E + e);
        atomicAdd(&s_h[d >> shift], 1u);
    }
    __syncthreads();
    for (int i = t; i < 512; i += 256)
        if (s_h[i]) atomicAdd(&bcnt[i], s_h[i]);
}

// LDS-staged partition of raw edges into destination buckets. Each block:
// (a) self-detects width, (b) locally scans the global 512-bucket histogram
// (replaces the scan_buckets dispatch), (c) histograms its own 4096 edges in
// LDS, (d) reserves per-bucket output runs with ONE global atomic per
// non-empty bucket on the zeroed bcur0 array, (e) scatters via LDS and
// flushes cursor-ordered contiguous runs (coalesced plain stores).
__global__ __launch_bounds__(256) void partition(const void* ei, const unsigned* __restrict__ bcnt,
                                                 unsigned* bcur0, long long* pout,
                                                 int E, int B, int shift) {
    __shared__ unsigned s_hist[512], s_off[512], s_gbase[512], s_pref[512], s_bbase[512];
    __shared__ unsigned wsum[4];
    __shared__ unsigned s_or[256];
    __shared__ int s_flag;
    __shared__ long long s_p[PCH];
    int t = threadIdx.x;
    long long base = (long long)blockIdx.x * PCH;
    for (int i = t; i < 512; i += 256) { s_hist[i] = 0u; s_off[i] = 0u; }
    int idx64 = detect_idx64(ei, E, s_or, &s_flag);

    // local exclusive scan of global bucket counts -> s_bbase
    {
        unsigned v0 = bcnt[2 * t], v1 = bcnt[2 * t + 1];
        unsigned ps = v0 + v1;
        unsigned s = ps;
        int lane = t & 63;
#pragma unroll
        for (int off = 1; off < 64; off <<= 1) {
            unsigned u = __shfl_up(s, off, 64);
            if (lane >= off) s += u;
        }
        int w = t >> 6;
        if (lane == 63) wsum[w] = s;
        __syncthreads();
        unsigned woff = 0;
        for (int j = 0; j < w; j++) woff += wsum[j];
        unsigned excl = woff + s - ps;
        s_bbase[2 * t] = excl;
        s_bbase[2 * t + 1] = excl + v0;
    }
    __syncthreads();

    // load own edges into registers, LDS histogram
    int d_[PCH / 256], s_[PCH / 256];
#pragma unroll 4
    for (int j = 0; j < PCH / 256; j++) {
        long long e = base + j * 256 + t;
        if (e < E) {
            d_[j] = edge_at(ei, idx64, (long long)E + e);
            s_[j] = edge_at(ei, idx64, e);
            atomicAdd(&s_hist[d_[j] >> shift], 1u);
        } else d_[j] = -1;
    }
    __syncthreads();

    // exclusive scan of local 512 counts -> s_pref
    {
        unsigned v0 = s_hist[2 * t], v1 = s_hist[2 * t + 1];
        unsigned ps = v0 + v1;
        unsigned s = ps;
        int lane = t & 63;
#pragma unroll
        for (int off = 1; off < 64; off <<= 1) {
            unsigned u = __shfl_up(s, off, 64);
            if (lane >= off) s += u;
        }
        int w = t >> 6;
        if (lane == 63) wsum[w] = s;
        __syncthreads();
        unsigned woff = 0;
        for (int j = 0; j < w; j++) woff += wsum[j];
        unsigned excl = woff + s - ps;
        s_pref[2 * t] = excl;
        s_pref[2 * t + 1] = excl + v0;
    }
    __syncthreads();

    for (int i = t; i < B; i += 256)
        if (s_hist[i]) s_gbase[i] = s_bbase[i] + atomicAdd(&bcur0[i], s_hist[i]);
#pragma unroll 4
    for (int j = 0; j < PCH / 256; j++)
        if (d_[j] >= 0) {
            int b = d_[j] >> shift;
            unsigned p = s_pref[b] + atomicAdd(&s_off[b], 1u);
            s_p[p] = ((long long)s_[j] << 32) | (unsigned)d_[j];
        }
    __syncthreads();
    long long rem = (long long)E - base;
    unsigned tot = (rem < PCH) ? (unsigned)rem : (unsigned)PCH;
    for (unsigned i = t; i < tot; i += 256) {
        int lo = 0, hi = B - 1;                 // largest b with s_pref[b] <= i
        while (lo < hi) {
            int mid = (lo + hi + 1) >> 1;
            if (s_pref[mid] <= i) lo = mid; else hi = mid - 1;
        }
        pout[s_gbase[lo] + (i - s_pref[lo])] = s_p[i];
    }
}

// One block per bucket (<=512 nodes). Recomputes bucket bases locally from
// bcnt (no bbase array / no scan dispatch). Degree histogram, prefix scan,
// dis, and CSR fill all via LDS counters -- zero global scattered atomics.
__global__ __launch_bounds__(256) void build_csr(const long long* __restrict__ pairs,
                                                 const unsigned* __restrict__ bcnt,
                                                 unsigned* deg, unsigned* row_start,
                                                 float* dis, int* col_src,
                                                 int N, int shift) {
    __shared__ unsigned cnt[512], cur[512], pref[512];
    __shared__ unsigned s_bb[513];
    __shared__ unsigned wsum[4];
    int b = blockIdx.x, t = threadIdx.x;
    int npb = 1 << shift;
    if (npb > 512) npb = 512;                   // defensive; caller guarantees <=512
    int nodeLo = b << shift;

    // local exclusive scan of global bucket counts -> bucket [lo,hi)
    {
        unsigned v0 = bcnt[2 * t], v1 = bcnt[2 * t + 1];
        unsigned ps = v0 + v1;
        unsigned s = ps;
        int lane = t & 63;
#pragma unroll
        for (int off = 1; off < 64; off <<= 1) {
            unsigned u = __shfl_up(s, off, 64);
            if (lane >= off) s += u;
        }
        int w = t >> 6;
        if (lane == 63) wsum[w] = s;
        __syncthreads();
        unsigned woff = 0;
        for (int j = 0; j < w; j++) woff += wsum[j];
        unsigned excl = woff + s - ps;
        s_bb[2 * t] = excl;
        s_bb[2 * t + 1] = excl + v0;
        if (t == 255) s_bb[512] = excl + ps;
    }
    __syncthreads();
    unsigned lo = s_bb[b], hi = s_bb[b + 1];

    for (int i = t; i < npb; i += 256) cnt[i] = 0u;
    __syncthreads();
    for (unsigned e = lo + t; e < hi; e += 256) {
        int d = (int)pairs[e];
        atomicAdd(&cnt[d - nodeLo], 1u);
    }
    __syncthreads();
    // exclusive scan of npb (<=512) counts, 2 per thread
    unsigned v0 = (2 * t < npb) ? cnt[2 * t] : 0u;
    unsigned v1 = (2 * t + 1 < npb) ? cnt[2 * t + 1] : 0u;
    unsigned ps = v0 + v1;
    unsigned s = ps;
    int lane = t & 63;
#pragma unroll
    for (int off = 1; off < 64; off <<= 1) {
        unsigned u = __shfl_up(s, off, 64);
        if (lane >= off) s += u;
    }
    int w = t >> 6;
    if (lane == 63) wsum[w] = s;
    __syncthreads();
    unsigned woff = 0;
    for (int j = 0; j < w; j++) woff += wsum[j];
    unsigned excl = woff + s - ps;
    if (2 * t < npb) pref[2 * t] = excl;
    if (2 * t + 1 < npb) pref[2 * t + 1] = excl + v0;
    __syncthreads();
    for (int i = t; i < npb; i += 256) {
        int node = nodeLo + i;
        unsigned rs = lo + pref[i];
        if (node < N) {
            unsigned c = cnt[i];
            deg[node] = c;
            row_start[node] = rs;
            dis[node] = rsqrtf((float)c + 1.0f);   // +1 self-loop
        }
        cur[i] = rs;
    }
    __syncthreads();
    for (unsigned e = lo + t; e < hi; e += 256) {
        long long v = pairs[e];
        int d = (int)v;
        int sv = (int)(v >> 32);
        unsigned pos = atomicAdd(&cur[d - nodeLo], 1u);
        col_src[pos] = sv;
    }
}

// xps = dis[row] * (x @ W), bf16 MFMA, fp32 x in / packed-bf16 out (pre-scaled).
// W transpose+bf16-convert fused: each block stages Wt into LDS (padded row
// stride 136 shorts = 272B -> max 2-way bank aliasing on the b128 reads,
// free per the LDS model). Removes the transposeW dispatch.
// Operand swap: mfma(Wfrag, Xfrag, acc) -> lane holds out[row=rowBase+l15][col=quad*4+reg]
__global__ __launch_bounds__(256) void gemm_xw(const float* __restrict__ x,
                                               const float* __restrict__ W,
                                               const float* __restrict__ dis,
                                               unsigned short* __restrict__ xps, int N) {
    __shared__ unsigned short wt[128 * 136];
    int tid = threadIdx.x;
    for (int idx = tid; idx < DIM * DIM; idx += 256) {
        int k = idx >> 7, n = idx & 127;        // idx = k*128+n -> coalesced W read
        wt[n * 136 + k] = f2bf(W[idx]);
    }
    __syncthreads();

    int wv = tid >> 6, lane = tid & 63;
    int l15 = lane & 15, quad = lane >> 4;
    int rowBase = blockIdx.x * 128 + wv * 32;

    f32x4 acc[2][8];
#pragma unroll
    for (int mt = 0; mt < 2; mt++)
#pragma unroll
        for (int nt = 0; nt < 8; nt++)
            acc[mt][nt] = (f32x4){0.f, 0.f, 0.f, 0.f};

#pragma unroll
    for (int k0 = 0; k0 < DIM; k0 += 32) {
        bf16x8 aa[2], bb[8];
#pragma unroll
        for (int mt = 0; mt < 2; mt++) {
            int r = rowBase + mt * 16 + l15;
            if (r > N - 1) r = N - 1;           // clamp; garbage rows never stored
            const float* xf = x + (size_t)r * DIM + k0 + quad * 8;
            float4 u0 = ((const float4*)xf)[0];
            float4 u1 = ((const float4*)xf)[1];
            bf16x8 a;
            a[0] = (short)f2bf(u0.x); a[1] = (short)f2bf(u0.y);
            a[2] = (short)f2bf(u0.z); a[3] = (short)f2bf(u0.w);
            a[4] = (short)f2bf(u1.x); a[5] = (short)f2bf(u1.y);
            a[6] = (short)f2bf(u1.z); a[7] = (short)f2bf(u1.w);
            aa[mt] = a;
        }
#pragma unroll
        for (int nt = 0; nt < 8; nt++)
            bb[nt] = *(const bf16x8*)(wt + (nt * 16 + l15) * 136 + k0 + quad * 8);
#pragma unroll
        for (int mt = 0; mt < 2; mt++)
#pragma unroll
            for (int nt = 0; nt < 8; nt++)
                acc[mt][nt] = __builtin_amdgcn_mfma_f32_16x16x32_bf16(bb[nt], aa[mt], acc[mt][nt], 0, 0, 0);
    }

#pragma unroll
    for (int mt = 0; mt < 2; mt++) {
        int r = rowBase + mt * 16 + l15;
        if (r < N) {
            float sc = dis[r];                  // pre-scale by source-side dis
#pragma unroll
            for (int nt = 0; nt < 8; nt++) {
                int c0 = nt * 16 + quad * 4;
                ushort4 o;
                o.x = f2bf(acc[mt][nt][0] * sc);
                o.y = f2bf(acc[mt][nt][1] * sc);
                o.z = f2bf(acc[mt][nt][2] * sc);
                o.w = f2bf(acc[mt][nt][3] * sc);
                *(ushort4*)(xps + (size_t)r * DIM + c0) = o;
            }
        }
    }
}

// One wave per node. 16 lanes per edge row (uint4 = 16B = 8 bf16 each), 4 edge
// slots per wave, inner loop unrolled x2 (8 slots / iter) for MLP. Indices are
// prefetched 64-at-a-time (one coalesced load) and shfl-broadcast. Self-loop is
// virtual slot `cnt` (index wid). out[d] = dis[d] * sum(xps).
__global__ __launch_bounds__(256) void aggregate(const unsigned short* __restrict__ xps,
                                                 const unsigned* __restrict__ row_start,
                                                 const unsigned* __restrict__ deg,
                                                 const float* __restrict__ dis,
                                                 const int* __restrict__ col_src,
                                                 float* __restrict__ out, int N) {
    int wid = (int)((blockIdx.x * 256 + threadIdx.x) >> 6);
    if (wid >= N) return;
    int lane = threadIdx.x & 63;
    int grp = lane >> 4, lin = lane & 15;
    const uint4* xp4 = (const uint4*)xps;       // row = 16 x uint4

    float acc[8];
#pragma unroll
    for (int j = 0; j < 8; j++) acc[j] = 0.f;

    unsigned rs = row_start[wid];
    unsigned cnt = deg[wid];
    unsigned tot = cnt + 1;                      // + virtual self slot

    for (unsigned base = 0; base < tot; base += 64) {
        unsigned slot = base + (unsigned)lane;
        int idx = (slot < cnt) ? col_src[rs + slot] : wid;   // invalid/self -> wid (safe)
        unsigned rem = tot - base; if (rem > 64) rem = 64;
        for (unsigned q = 0; q * 8 < rem; q++) {
            unsigned sl0 = q * 8 + (unsigned)grp;
            unsigned sl1 = sl0 + 4;
            int s0 = __shfl(idx, (int)sl0, 64);
            int s1 = __shfl(idx, (int)sl1, 64);
            float m0 = (sl0 < rem) ? 1.f : 0.f;
            float m1 = (sl1 < rem) ? 1.f : 0.f;
            uint4 v0 = xp4[(size_t)s0 * 16 + lin];
            uint4 v1 = xp4[(size_t)s1 * 16 + lin];
            acc[0] = fmaf(bfu_lo(v0.x), m0, acc[0]);
            acc[1] = fmaf(bfu_hi(v0.x), m0, acc[1]);
            acc[2] = fmaf(bfu_lo(v0.y), m0, acc[2]);
            acc[3] = fmaf(bfu_hi(v0.y), m0, acc[3]);
            acc[4] = fmaf(bfu_lo(v0.z), m0, acc[4]);
            acc[5] = fmaf(bfu_hi(v0.z), m0, acc[5]);
            acc[6] = fmaf(bfu_lo(v0.w), m0, acc[6]);
            acc[7] = fmaf(bfu_hi(v0.w), m0, acc[7]);
            acc[0] = fmaf(bfu_lo(v1.x), m1, acc[0]);
            acc[1] = fmaf(bfu_hi(v1.x), m1, acc[1]);
            acc[2] = fmaf(bfu_lo(v1.y), m1, acc[2]);
            acc[3] = fmaf(bfu_hi(v1.y), m1, acc[3]);
            acc[4] = fmaf(bfu_lo(v1.z), m1, acc[4]);
            acc[5] = fmaf(bfu_hi(v1.z), m1, acc[5]);
            acc[6] = fmaf(bfu_lo(v1.w), m1, acc[6]);
            acc[7] = fmaf(bfu_hi(v1.w), m1, acc[7]);
        }
    }

    // reduce across the 4 groups (lanes differing in bits 4 and 5)
#pragma unroll
    for (int j = 0; j < 8; j++) {
        acc[j] += __shfl_xor(acc[j], 16, 64);
        acc[j] += __shfl_xor(acc[j], 32, 64);
    }

    float di = dis[wid];
    if (grp < 2) {                               // 32 lanes store the 512B row
        int jb = (grp & 1) * 4;
        float4 o;
        o.x = acc[jb + 0] * di;
        o.y = acc[jb + 1] * di;
        o.z = acc[jb + 2] * di;
        o.w = acc[jb + 3] * di;
        *(float4*)(out + (size_t)wid * DIM + lin * 8 + jb) = o;
    }
}

extern "C" void kernel_launch(void* const* d_in, const int* in_sizes, int n_in,
                              void* d_out, int out_size, void* d_ws, size_t ws_size,
                              hipStream_t stream) {
    const int N = in_sizes[0] / DIM;
    const int E = in_sizes[1] / 2;
    const float* x = (const float*)d_in[0];                     // fp32 [N][128]
    const void* ei = d_in[1];                                   // int32 or int64 [2][E]
    const float* W = (const float*)d_in[2];                     // fp32 [128][128]
    float* out = (float*)d_out;                                 // fp32 [N][128]

    // bucket geometry: 2^shift nodes per bucket, B <= 512 buckets; npb <= 512
    // (holds for N <= 262144; this problem is N=100000 -> shift=8, B=391)
    int shift = 8;
    while ((((long long)N + (1LL << shift) - 1) >> shift) > 512 && shift < 9) shift++;
    int B = (int)(((long long)N + (1LL << shift) - 1) >> shift);

    char* wsp = (char*)d_ws;
    size_t off = 0;
    auto alloc = [&](size_t b) { void* p = wsp + off; off += (b + 255) & ~(size_t)255; return p; };
    unsigned* bcnt       = (unsigned*)alloc(4096);              // [0..511]=bcnt, [512..1023]=bcur0
    unsigned* bcur0      = bcnt + 512;
    unsigned* deg        = (unsigned*)alloc((size_t)N * 4);
    unsigned* row_start  = (unsigned*)alloc((size_t)N * 4);
    float*    dis        = (float*)alloc((size_t)N * 4);
    int*      col_src    = (int*)alloc((size_t)E * 4);
    unsigned short* xps  = (unsigned short*)alloc((size_t)N * DIM * 2);

    // pairs alias the xps region (E*8 = 12.8MB <= N*DIM*2 = 25.6MB): dead
    // before gemm_xw writes xps (stream-ordered), so no extra workspace.
    long long* pairs = (long long*)xps;
    if ((size_t)E * 8 > (size_t)N * DIM * 2 && off + (size_t)E * 8 <= ws_size)
        pairs = (long long*)alloc((size_t)E * 8);

    hipMemsetAsync(bcnt, 0, 4096, stream);
    hist_detect<<<512, 256, 0, stream>>>(ei, bcnt, E, shift);
    partition<<<(E + PCH - 1) / PCH, 256, 0, stream>>>(ei, bcnt, bcur0, pairs, E, B, shift);
    build_csr<<<B, 256, 0, stream>>>(pairs, bcnt, deg, row_start, dis, col_src, N, shift);
    gemm_xw<<<(N + 127) / 128, 256, 0, stream>>>(x, W, dis, xps, N);
    aggregate<<<(N + 3) / 4, 256, 0, stream>>>(xps, row_start, deg, dis, col_src, out, N);
}